// Round 3
// baseline (15.900 us; speedup 1.0000x reference)
//
#include <hip/hip_runtime.h>

// LinearClassification: loss = -2 * sum_i out[i, label[i]] / (B * V)
// B = 4096, V = 50257 -> 4096 scattered fp32 gathers + scalar reduce.
// Latency-bound. This version spreads the gathers over 16 workgroups
// (16 CUs, all XCDs) to parallelize memory-issue, with a deterministic
// last-block-ticket cross-block reduction (fp64 accumulate; fixed
// summation order -> bit-deterministic result).

#define BLOCK 256

__global__ __launch_bounds__(BLOCK)
void LinearClassification_71167608095256_kernel(const float* __restrict__ outm,
                                                const int* __restrict__ lab32,
                                                float* __restrict__ res,
                                                unsigned int* __restrict__ counter,
                                                double* __restrict__ partials,
                                                int B, long long V, int nblocks) {
    const int tid  = threadIdx.x;
    const int gtid = blockIdx.x * BLOCK + tid;
    const int lane = tid & 63;
    const int wave = tid >> 6;

    __shared__ int    s_is64;
    __shared__ double s_part[BLOCK / 64];

    // --- Layout detection (every block, same 64 odd words -> L2 broadcast).
    // int64-LE label layout => odd 32-bit words are zero high-halves.
    // int32 layout => they are random labels in [0, 50257): P(64 zeros) ~ 0.
    int nonzero = 0;
    if (wave == 0) {
        int j = 2 * lane + 1;
        if (j < B) nonzero = (lab32[j] != 0);
    }

    // --- Speculative int32-layout label load + gather (both in-bounds under
    // either layout: word gtid < B <= 2B words; spec index is a label or 0).
    int   labv = 0;
    float gv   = 0.0f;
    if (gtid < B) {
        labv = lab32[gtid];
        gv   = outm[(long long)gtid * V + (long long)labv];
    }

    if (wave == 0) {
        unsigned long long ball = __ballot(nonzero);
        if (lane == 0) s_is64 = (ball == 0ull) ? 1 : 0;
    }
    __syncthreads();

    double acc = 0.0;
    if (gtid < B) {
        if (!s_is64) {
            acc = (double)gv;                 // fast path: int32 labels
        } else {                              // int64 layout: re-gather
            const long long idx = (long long)lab32[2 * gtid];
            acc = (double)outm[(long long)gtid * V + idx];
        }
    }

    // --- Block reduction: wave shuffle tree, then LDS across 4 waves.
    #pragma unroll
    for (int off = 32; off > 0; off >>= 1)
        acc += __shfl_down(acc, off, 64);
    if (lane == 0) s_part[wave] = acc;
    __syncthreads();

    if (tid == 0) {
        double t = 0.0;
        #pragma unroll
        for (int w = 0; w < BLOCK / 64; ++w) t += s_part[w];

        // Publish partial (device scope, release), then take a ticket.
        __hip_atomic_store((unsigned long long*)&partials[blockIdx.x],
                           __builtin_bit_cast(unsigned long long, t),
                           __ATOMIC_RELEASE, __HIP_MEMORY_SCOPE_AGENT);
        unsigned int old = __hip_atomic_fetch_add(counter, 1u, __ATOMIC_ACQ_REL,
                                                  __HIP_MEMORY_SCOPE_AGENT);
        if (old == (unsigned int)(nblocks - 1)) {
            // Last block: all partials published. Sum in FIXED index order
            // (bit-deterministic regardless of block completion order).
            double t2 = 0.0;
            for (int b = 0; b < nblocks; ++b) {
                unsigned long long u = __hip_atomic_load(
                    (unsigned long long*)&partials[b],
                    __ATOMIC_ACQUIRE, __HIP_MEMORY_SCOPE_AGENT);
                t2 += __builtin_bit_cast(double, u);
            }
            res[0] = (float)(-2.0 * t2 / ((double)B * (double)V));
        }
    }
}

extern "C" void kernel_launch(void* const* d_in, const int* in_sizes, int n_in,
                              void* d_out, int out_size, void* d_ws, size_t ws_size,
                              hipStream_t stream) {
    const float* outm = (const float*)d_in[0];
    const int*   lab  = (const int*)d_in[1];
    float*       res  = (float*)d_out;

    const int B = in_sizes[1];                       // 4096
    const long long V = (long long)in_sizes[0] / B;  // 50257
    const int nblocks = (B + BLOCK - 1) / BLOCK;     // 16

    // d_ws layout: [0,4) ticket counter; [64, 64+8*nblocks) double partials.
    unsigned int* counter  = (unsigned int*)d_ws;
    double*       partials = (double*)((char*)d_ws + 64);

    hipMemsetAsync(counter, 0, sizeof(unsigned int), stream);
    LinearClassification_71167608095256_kernel<<<nblocks, BLOCK, 0, stream>>>(
        outm, lab, res, counter, partials, B, V, nblocks);
}